// Round 2
// baseline (157.428 us; speedup 1.0000x reference)
//
#include <hip/hip_runtime.h>
#include <hip/hip_bf16.h>
#include <cstdint>
#include <cstddef>

// StreamingAttentionBlock: B=2, T=2048, DIM=1024, H=16, hd=64, window=3 keys
// I/O: fp32. Internal: bf16 MFMA, fp32 accumulation.
// R11: GEMM1 = 256x256 tile, BK=32, 4-deep K-slab ring (provably race-free):
//   - step s reads ring[s&3]; stages tile s+3 into ring[(s-1)&3] (never the
//     ring being read; last read of that ring was step s-1, behind a barrier)
//   - counted vmcnt(12) per step (3 stage-groups in flight), never 0 in loop
//   - XOR swizzle byte ^= ((row>>1)&3)<<4 (64B rows): 8-way ds_read_b128
//     conflict -> 2-way (free). Applied both-sides: linear gld_lds dest +
//     inverse-swizzled global source + swizzled ds_read (rule #21)
//   - s_setprio(1) around the 32-MFMA cluster (T5), sched_barrier fences
// R10 post-mortem: 8-phase half-tile schedule raced — output-quadrant phases
// read LDS rows across BOTH halves (wm=1 reads rows 128..191 in "Q0"), so
// staging A(t+2) into As[cur] clobbered rows still live. Ring design kills
// that class of bug: stage target != read ring, always barrier-separated.
#define T_SEQ 2048
#define NBATCH 2
#define DIMSZ 1024
#define NHEAD 16
#define HDIM 64

typedef float f32x4 __attribute__((ext_vector_type(4)));
typedef short bf16x8 __attribute__((ext_vector_type(8)));

// async global->LDS, 16B per lane. LDS dest = wave-uniform base + lane*16.
__device__ __forceinline__ void gld_lds16(const __hip_bfloat16* g, __hip_bfloat16* l) {
    __builtin_amdgcn_global_load_lds(
        (const __attribute__((address_space(1))) unsigned int*)g,
        (__attribute__((address_space(3))) unsigned int*)l,
        16, 0, 0);
}

__device__ __forceinline__ float bf2f(unsigned short u) {
    union { unsigned int i; float f; } c; c.i = (unsigned int)u << 16; return c.f;
}

// -------- fused prep: convert x -> bf16; convert+transpose both weights --------
__global__ __launch_bounds__(256) void prep(
    const float* __restrict__ x,      __hip_bfloat16* __restrict__ xb,
    const float* __restrict__ wqkv,   __hip_bfloat16* __restrict__ wqkvT,
    const float* __restrict__ wproj,  __hip_bfloat16* __restrict__ wprojT)
{
    __shared__ float tile[32][33];
    const int b = blockIdx.x;
    if (b < 4096) {
        int i = (b * 256 + threadIdx.x) * 4;
        float4 v = *(const float4*)(x + i);
        union { __hip_bfloat16 h[4]; ushort4 u; } pk;
        pk.h[0] = __hip_bfloat16(v.x); pk.h[1] = __hip_bfloat16(v.y);
        pk.h[2] = __hip_bfloat16(v.z); pk.h[3] = __hip_bfloat16(v.w);
        *(ushort4*)(xb + i) = pk.u;
        return;
    }
    const float* in; __hip_bfloat16* out; int C, c0, r0;
    if (b < 7168) {
        int bb = b - 4096; in = wqkv; out = wqkvT; C = 3072;
        c0 = (bb % 96) * 32; r0 = (bb / 96) * 32;
    } else {
        int bb = b - 7168; in = wproj; out = wprojT; C = 1024;
        c0 = (bb & 31) * 32; r0 = (bb >> 5) * 32;
    }
    const int tx = threadIdx.x & 31, ty = threadIdx.x >> 5;
#pragma unroll
    for (int p = 0; p < 32; p += 8)
        tile[ty + p][tx] = in[(size_t)(r0 + ty + p) * C + c0 + tx];
    __syncthreads();
#pragma unroll
    for (int p = 0; p < 32; p += 8)
        out[(size_t)(c0 + ty + p) * 1024 + r0 + tx] = __hip_bfloat16(tile[tx][ty + p]);
}

// -------- GEMM1: 256x256 tile, BK=32, 4-ring counted-vmcnt pipeline --------
#define BAR() do { asm volatile("" ::: "memory"); __builtin_amdgcn_s_barrier(); \
                   asm volatile("" ::: "memory"); } while (0)

// stage one 256x32 K-slab of G (tile kt) into ring buffer rb.
// 512 threads x 16B = 8 KiB/issue = 128 rows x 64B; 2 issues cover 256 rows.
// LDS dest is linear (= wave-uniform + lane*16); global source column is
// pre-swizzled with the involution so swizzled ds_read recovers true data.
#define STAGE1(G, S, rb, kt)                                                   \
    do {                                                                       \
        _Pragma("unroll")                                                      \
        for (int s_ = 0; s_ < 2; ++s_) {                                       \
            int row_ = s_ * 128 + (tid >> 2);                                  \
            int cbg_ = scb ^ (((row_ >> 1) & 3) << 4);                        \
            gld_lds16(G + (size_t)row_ * K + (kt) * 32 + (cbg_ >> 1),          \
                      &S[rb][row_ * 32 + (scb >> 1)]);                         \
        }                                                                      \
    } while (0)

__global__ __launch_bounds__(512, 2) void gemm256_ring(
    const __hip_bfloat16* __restrict__ A,
    const __hip_bfloat16* __restrict__ Bt,
    __hip_bfloat16* __restrict__ C,
    int M, int N, int K)
{
    __shared__ __align__(16) __hip_bfloat16 As[4][256 * 32];   // 64 KiB
    __shared__ __align__(16) __hip_bfloat16 Bs[4][256 * 32];   // 64 KiB

    const int tid  = threadIdx.x;
    const int lane = tid & 63;
    const int wv   = tid >> 6;
    const int wm   = wv >> 2;       // 0..1 -> 128 output rows
    const int wn   = wv & 3;        // 0..3 -> 64 output cols

    // bijective XCD swizzle (gridDim.x % 8 == 0)
    const int nwg = gridDim.x;
    const int cpx = nwg >> 3;
    const int bid = blockIdx.x;
    const int swb = (bid & 7) * cpx + (bid >> 3);
    const int nbn = N >> 8;
    const int bm = swb / nbn, bn = swb % nbn;

    const int NT = K >> 5;          // K-slabs of 32

    const __hip_bfloat16* Ag = A  + (size_t)(bm << 8) * K;
    const __hip_bfloat16* Bg = Bt + (size_t)(bn << 8) * K;

    // staging lane geometry: row = tid>>2 (128 rows/issue), 16B col = tid&3
    const int scb = (tid & 3) << 4;      // byte col within 64B row

    // fragment lane geometry
    const int fm = lane & 15;
    const int fq = (lane >> 4) << 3;     // element col (0,8,16,24) within 32

    f32x4 acc[8][4] = {};

    // ---- prologue: stage slabs 0,1,2 into rings 0,1,2 (12 loads/thread) ----
    STAGE1(Ag, As, 0, 0); STAGE1(Bg, Bs, 0, 0);
    STAGE1(Ag, As, 1, 1); STAGE1(Bg, Bs, 1, 1);
    STAGE1(Ag, As, 2, 2); STAGE1(Bg, Bs, 2, 2);

    for (int s = 0; s < NT; ++s) {
        int kt3 = s + 3; if (kt3 >= NT) kt3 -= NT;   // wrapped slabs: staged into
        const int rcur = s & 3;                      // dead rings, never read
        const int rnxt = kt3 & 3;                    // == (s-1)&3, != rcur

        STAGE1(Ag, As, rnxt, kt3);
        STAGE1(Bg, Bs, rnxt, kt3);

        // 3 stage-groups (12 loads) stay in flight; waits only for slab s.
        asm volatile("s_waitcnt vmcnt(12)" ::: "memory");
        BAR();

        bf16x8 af[8], bfv[4];
#pragma unroll
        for (int i = 0; i < 8; ++i) {
            int row_ = wm * 128 + i * 16 + fm;
            int ce_  = fq ^ (((row_ >> 1) & 3) << 3);
            af[i] = *(const bf16x8*)&As[rcur][row_ * 32 + ce_];
        }
#pragma unroll
        for (int j = 0; j < 4; ++j) {
            int row_ = wn * 64 + j * 16 + fm;
            int ce_  = fq ^ (((row_ >> 1) & 3) << 3);
            bfv[j] = *(const bf16x8*)&Bs[rcur][row_ * 32 + ce_];
        }

        __builtin_amdgcn_sched_barrier(0);
        __builtin_amdgcn_s_setprio(1);
#pragma unroll
        for (int i = 0; i < 8; ++i)
#pragma unroll
            for (int j = 0; j < 4; ++j)
                acc[i][j] = __builtin_amdgcn_mfma_f32_16x16x32_bf16(
                    af[i], bfv[j], acc[i][j], 0, 0, 0);
        __builtin_amdgcn_s_setprio(0);
        __builtin_amdgcn_sched_barrier(0);
        BAR();
    }
    asm volatile("s_waitcnt vmcnt(0)" ::: "memory");  // drain wrapped stages

    // C/D layout: col=lane&15, row=(lane>>4)*4+reg  [m89-verified]
    const int fcol  = lane & 15;
    const int frow4 = (lane >> 4) << 2;
    const int cm0 = (bm << 8) + wm * 128;
    const int cn0 = (bn << 8) + wn * 64;
#pragma unroll
    for (int nj = 0; nj < 4; ++nj) {
        int col = cn0 + nj * 16 + fcol;
#pragma unroll
        for (int mi = 0; mi < 8; ++mi)
#pragma unroll
            for (int r = 0; r < 4; ++r) {
                int row = cm0 + mi * 16 + frow4 + r;
                C[(size_t)row * N + col] = __hip_bfloat16(acc[mi][nj][r]);
            }
    }
}

// -------- GEMM2: 64x128 tile, BK=64 (512 blocks = 2/CU), fp32 out + bias --------
__global__ __launch_bounds__(256) void gemm_bt_64(
    const __hip_bfloat16* __restrict__ A,
    const __hip_bfloat16* __restrict__ Bt,
    const float* __restrict__ bias,
    float* __restrict__ C,
    int M, int N, int K)
{
    __shared__ __align__(16) __hip_bfloat16 As2[2 * 64 * 32];
    __shared__ __align__(16) __hip_bfloat16 Bs2[2 * 128 * 32];

    const int tid  = threadIdx.x;
    const int wv   = tid >> 6;
    const int lane = tid & 63;
    const int bn   = blockIdx.x, bm = blockIdx.y;
    const int wm   = wv >> 1, wn = wv & 1;

    f32x4 acc[2][4] = {};

    const int srow = lane >> 2;
    const int scol = (lane & 3) * 8;

    const __hip_bfloat16* Ag = A  + (size_t)(bm * 64) * K;
    const __hip_bfloat16* Bg = Bt + (size_t)(bn * 128) * K;

    const int fm = lane & 15;
    const int fq = (lane >> 4) * 8;

    for (int kk = 0; kk < K; kk += 64) {
#pragma unroll
        for (int kh = 0; kh < 2; ++kh) {
            {
                int row = wv * 16 + srow;                     // 0..63
                gld_lds16(Ag + (size_t)row * K + kk + kh * 32 + scol,
                          As2 + kh * 2048 + row * 32 + scol);
            }
#pragma unroll
            for (int it = 0; it < 2; ++it) {
                int row = (it * 4 + wv) * 16 + srow;          // 0..127
                gld_lds16(Bg + (size_t)row * K + kk + kh * 32 + scol,
                          Bs2 + kh * 4096 + row * 32 + scol);
            }
        }
        __syncthreads();

#pragma unroll
        for (int kh = 0; kh < 2; ++kh) {
            bf16x8 af[2], bfr[4];
#pragma unroll
            for (int i = 0; i < 2; ++i)
                af[i] = *(const bf16x8*)(As2 + kh * 2048 + (wm * 32 + i * 16 + fm) * 32 + fq);
#pragma unroll
            for (int j = 0; j < 4; ++j)
                bfr[j] = *(const bf16x8*)(Bs2 + kh * 4096 + (wn * 64 + j * 16 + fm) * 32 + fq);
#pragma unroll
            for (int i = 0; i < 2; ++i)
#pragma unroll
                for (int j = 0; j < 4; ++j)
                    acc[i][j] = __builtin_amdgcn_mfma_f32_16x16x32_bf16(af[i], bfr[j], acc[i][j], 0, 0, 0);
        }
        __syncthreads();
    }

    const int fcol  = lane & 15;
    const int frow4 = (lane >> 4) * 4;
    const int cm0 = bm * 64 + wm * 32;
    const int cn0 = bn * 128 + wn * 64;
#pragma unroll
    for (int j = 0; j < 4; ++j) {
        int col = cn0 + j * 16 + fcol;
        float bv = bias[col];
#pragma unroll
        for (int i = 0; i < 2; ++i)
#pragma unroll
            for (int r = 0; r < 4; ++r) {
                int row = cm0 + i * 16 + frow4 + r;
                C[(size_t)row * N + col] = acc[i][j][r] + bv;
            }
    }
}

// -------- banded attention, vectorized: one block per token, thread = 4-dim chunk --------
__global__ __launch_bounds__(256) void attn_banded(
    const __hip_bfloat16* __restrict__ qkv,   // (B*T, 3*DIM): [q | k | v]
    __hip_bfloat16* __restrict__ o)           // (B*T, DIM)
{
    const int t4 = threadIdx.x;          // dim-chunk index: dims [4*t4, 4*t4+4)
    const int r  = blockIdx.x;           // b*T + t
    const int t  = r & (T_SEQ - 1);
    const size_t rb = (size_t)r * (3 * DIMSZ);
    const int d0 = t4 * 4;

    ushort4 qu = *(const ushort4*)(qkv + rb + d0);
    float q0 = bf2f(qu.x), q1 = bf2f(qu.y), q2 = bf2f(qu.z), q3 = bf2f(qu.w);

    float s[3], vvx[3], vvy[3], vvz[3], vvw[3];
#pragma unroll
    for (int j = 0; j < 3; ++j) {
        bool ok = (t + j) < T_SEQ;       // masks seq end (and batch boundary)
        size_t rbj = ok ? rb + (size_t)j * (3 * DIMSZ) : rb;
        ushort4 ku = *(const ushort4*)(qkv + rbj + DIMSZ + d0);
        ushort4 vu = *(const ushort4*)(qkv + rbj + 2 * DIMSZ + d0);
        vvx[j] = bf2f(vu.x); vvy[j] = bf2f(vu.y); vvz[j] = bf2f(vu.z); vvw[j] = bf2f(vu.w);
        float d = q0 * bf2f(ku.x) + q1 * bf2f(ku.y) + q2 * bf2f(ku.z) + q3 * bf2f(ku.w);
#pragma unroll
        for (int off = 8; off > 0; off >>= 1)
            d += __shfl_xor(d, off, 64); // reduce within 16-lane head group
        s[j] = ok ? d * 0.125f : -1e30f; // scale = 64^-0.5
    }
    float m  = fmaxf(s[0], fmaxf(s[1], s[2]));
    float p0 = __expf(s[0] - m), p1 = __expf(s[1] - m), p2 = __expf(s[2] - m);
    float inv = 1.0f / (p0 + p1 + p2);
    union { __hip_bfloat16 h[4]; ushort4 uu; } pk;
    pk.h[0] = __hip_bfloat16((p0 * vvx[0] + p1 * vvx[1] + p2 * vvx[2]) * inv);
    pk.h[1] = __hip_bfloat16((p0 * vvy[0] + p1 * vvy[1] + p2 * vvy[2]) * inv);
    pk.h[2] = __hip_bfloat16((p0 * vvz[0] + p1 * vvz[1] + p2 * vvz[2]) * inv);
    pk.h[3] = __hip_bfloat16((p0 * vvw[0] + p1 * vvw[1] + p2 * vvw[2]) * inv);
    *(ushort4*)(o + (size_t)r * DIMSZ + d0) = pk.uu;
}

extern "C" void kernel_launch(void* const* d_in, const int* in_sizes, int n_in,
                              void* d_out, int out_size, void* d_ws, size_t ws_size,
                              hipStream_t stream) {
    const float* x      = (const float*)d_in[0];  // (B,T,DIM) fp32
    const float* w_qkv  = (const float*)d_in[1];  // (DIM, 3*DIM) fp32
    const float* w_proj = (const float*)d_in[2];  // (DIM, DIM) fp32
    const float* b_proj = (const float*)d_in[3];  // (DIM,) fp32
    float* out = (float*)d_out;                   // (B,T,DIM) fp32

    const int M = NBATCH * T_SEQ;   // 4096

    // workspace (bf16 intermediates):
    //   [0,8M)    xb (x bf16) -> reused as attn output after GEMM1 consumes it
    //   [8M,14M)  wqkvT  (3072x1024)
    //   [14M,16M) wprojT (1024x1024)
    //   [16M,40M) qkv    (4096x3072)
    char* ws = (char*)d_ws;
    __hip_bfloat16* xb     = (__hip_bfloat16*)(ws);
    __hip_bfloat16* attn   = (__hip_bfloat16*)(ws);            // reuse of xb region
    __hip_bfloat16* wqkvT  = (__hip_bfloat16*)(ws + (8u  << 20));
    __hip_bfloat16* wprojT = (__hip_bfloat16*)(ws + (14u << 20));
    __hip_bfloat16* qkv    = (__hip_bfloat16*)(ws + (16u << 20));

    // 1) fused prep: x->bf16, both weight convert+transposes
    prep<<<8192, 256, 0, stream>>>(x, xb, w_qkv, wqkvT, w_proj, wprojT);

    // 2) qkv = x @ w_qkv (4096 x 3072, K=1024): 16x12 = 192 blocks, 512 thr, 1/CU
    gemm256_ring<<<dim3((M / 256) * (3 * DIMSZ / 256)), 512, 0, stream>>>(
        xb, wqkvT, qkv, M, 3 * DIMSZ, DIMSZ);

    // 3) banded attention (3-key window) -> bf16 attn (reuses xb region)
    attn_banded<<<M, 256, 0, stream>>>(qkv, attn);

    // 4) out = attn @ w_proj + b_proj  (4096 x 1024): 8x64=512 blocks = 2/CU
    gemm_bt_64<<<dim3(DIMSZ / 128, M / 64), 256, 0, stream>>>(
        attn, wprojT, b_proj, out, M, DIMSZ, DIMSZ);
}

// Round 4
// 150.169 us; speedup vs baseline: 1.0483x; 1.0483x over previous
//
#include <hip/hip_runtime.h>
#include <hip/hip_bf16.h>
#include <cstdint>
#include <cstddef>

// StreamingAttentionBlock: B=2, T=2048, DIM=1024, H=16, hd=64, window=3 keys
// I/O: fp32. Internal: bf16 MFMA, fp32 accumulation.
// R13: R12's 4-phase 256x256 GEMM1 with READ CERTIFICATION SHIFTED ONE PHASE
// EARLY (fixes R12 NaN). Rule learned: a wave's vmcnt certifies only ITS OWN
// DMA loads; ds_reads of DMA-staged LDS are safe only after a barrier that
// FOLLOWS every wave's covering vmcnt. Schedule (steady state, groups = 2-load
// STAGEH units, 5 groups = vmcnt(10) always in flight):
//   ph0: read{Ah0,Bh0}(t) [certified @ph3(t-1)] | stage Ah1(t+1) | bar |
//        lgkm0 | 16 MFMA | vmcnt(10) -> certifies Bh1(t) | bar
//   ph1: read Bh1(t) | stage Ah0(t+2) | bar | lgkm0 | MFMA | vmcnt(10)
//        -> certifies Ah1(t) | bar
//   ph2: read Ah1(t) | stage Bh0(t+2) | bar | lgkm0 | MFMA | bar
//   ph3: stage Bh1(t+2) | MFMA (regs) | vmcnt(10) -> certifies {Ah0,Bh0}(t+1) | bar
// WAR side unchanged from R12 (re-audited clean): every stage target's last
// read completed >=1 barrier before the stage issue; tail wraps stage only
// into dead regions; vmcnt(0) once after the loop.
#define T_SEQ 2048
#define NBATCH 2
#define DIMSZ 1024
#define NHEAD 16
#define HDIM 64

typedef float f32x4 __attribute__((ext_vector_type(4)));
typedef short bf16x8 __attribute__((ext_vector_type(8)));

// async global->LDS, 16B per lane. LDS dest = wave-uniform base + lane*16.
__device__ __forceinline__ void gld_lds16(const __hip_bfloat16* g, __hip_bfloat16* l) {
    __builtin_amdgcn_global_load_lds(
        (const __attribute__((address_space(1))) unsigned int*)g,
        (__attribute__((address_space(3))) unsigned int*)l,
        16, 0, 0);
}

__device__ __forceinline__ float bf2f(unsigned short u) {
    union { unsigned int i; float f; } c; c.i = (unsigned int)u << 16; return c.f;
}

// -------- fused prep: convert x -> bf16; convert+transpose both weights --------
__global__ __launch_bounds__(256) void prep(
    const float* __restrict__ x,      __hip_bfloat16* __restrict__ xb,
    const float* __restrict__ wqkv,   __hip_bfloat16* __restrict__ wqkvT,
    const float* __restrict__ wproj,  __hip_bfloat16* __restrict__ wprojT)
{
    __shared__ float tile[32][33];
    const int b = blockIdx.x;
    if (b < 4096) {
        int i = (b * 256 + threadIdx.x) * 4;
        float4 v = *(const float4*)(x + i);
        union { __hip_bfloat16 h[4]; ushort4 u; } pk;
        pk.h[0] = __hip_bfloat16(v.x); pk.h[1] = __hip_bfloat16(v.y);
        pk.h[2] = __hip_bfloat16(v.z); pk.h[3] = __hip_bfloat16(v.w);
        *(ushort4*)(xb + i) = pk.u;
        return;
    }
    const float* in; __hip_bfloat16* out; int C, c0, r0;
    if (b < 7168) {
        int bb = b - 4096; in = wqkv; out = wqkvT; C = 3072;
        c0 = (bb % 96) * 32; r0 = (bb / 96) * 32;
    } else {
        int bb = b - 7168; in = wproj; out = wprojT; C = 1024;
        c0 = (bb & 31) * 32; r0 = (bb >> 5) * 32;
    }
    const int tx = threadIdx.x & 31, ty = threadIdx.x >> 5;
#pragma unroll
    for (int p = 0; p < 32; p += 8)
        tile[ty + p][tx] = in[(size_t)(r0 + ty + p) * C + c0 + tx];
    __syncthreads();
#pragma unroll
    for (int p = 0; p < 32; p += 8)
        out[(size_t)(c0 + ty + p) * 1024 + r0 + tx] = __hip_bfloat16(tile[tx][ty + p]);
}

// -------- GEMM1: 256x256 tile, BK=64, 4-phase certified pipeline --------
#define BAR() do { asm volatile("" ::: "memory"); __builtin_amdgcn_s_barrier(); \
                   asm volatile("" ::: "memory"); } while (0)
#define LGKM0_SB() do { asm volatile("s_waitcnt lgkmcnt(0)" ::: "memory"); \
                        __builtin_amdgcn_sched_barrier(0); } while (0)
#define VM10() asm volatile("s_waitcnt vmcnt(10)" ::: "memory")

// stage one 128x64 half-tile (tile kt, half h) of G into Sdst (linear LDS).
// 2 issues x 512 threads x 16B. Global 16B-col pre-swizzled: gu = u ^ (lr&7).
#define STAGEH(G, Sdst, kt, h)                                                  \
    do {                                                                        \
        _Pragma("unroll")                                                       \
        for (int s_ = 0; s_ < 2; ++s_) {                                        \
            int lr_ = s_ * 64 + (tid >> 3);                                     \
            int gu_ = (tid & 7) ^ (lr_ & 7);                                    \
            gld_lds16(G + (size_t)((h) * 128 + lr_) * K + (kt) * 64 + gu_ * 8,  \
                      (Sdst) + lr_ * 64 + (tid & 7) * 8);                       \
        }                                                                       \
    } while (0)

// read A-half qi -> a[4][2] (8 ds_read_b128, swizzled)
#define READ_A(buf, qi)                                                         \
    do {                                                                        \
        _Pragma("unroll")                                                       \
        for (int i_ = 0; i_ < 4; ++i_) {                                        \
            int lr_ = wq2 * 64 + i_ * 16 + fm;                                  \
            _Pragma("unroll")                                                   \
            for (int kh_ = 0; kh_ < 2; ++kh_) {                                 \
                int u_ = (kh_ * 4 + fu) ^ (lr_ & 7);                            \
                a[i_][kh_] = *(const bf16x8*)&As[buf][qi][lr_ * 64 + u_ * 8];   \
            }                                                                   \
        }                                                                       \
    } while (0)

// read B-half qj -> dst[2][2] (4 ds_read_b128, swizzled)
#define READ_B(buf, qj, dst)                                                    \
    do {                                                                        \
        _Pragma("unroll")                                                       \
        for (int j_ = 0; j_ < 2; ++j_) {                                        \
            int lr_ = wq4 * 32 + j_ * 16 + fm;                                  \
            _Pragma("unroll")                                                   \
            for (int kh_ = 0; kh_ < 2; ++kh_) {                                 \
                int u_ = (kh_ * 4 + fu) ^ (lr_ & 7);                            \
                dst[j_][kh_] = *(const bf16x8*)&Bs[buf][qj][lr_ * 64 + u_ * 8]; \
            }                                                                   \
        }                                                                       \
    } while (0)

#define MFMA16(QI, QJ, bsrc)                                                    \
    do {                                                                        \
        __builtin_amdgcn_s_setprio(1);                                          \
        _Pragma("unroll")                                                       \
        for (int i_ = 0; i_ < 4; ++i_)                                          \
            _Pragma("unroll")                                                   \
            for (int j_ = 0; j_ < 2; ++j_)                                      \
                _Pragma("unroll")                                               \
                for (int kh_ = 0; kh_ < 2; ++kh_)                               \
                    acc[QI][QJ][i_][j_] =                                       \
                        __builtin_amdgcn_mfma_f32_16x16x32_bf16(                \
                            a[i_][kh_], bsrc[j_][kh_],                          \
                            acc[QI][QJ][i_][j_], 0, 0, 0);                      \
        __builtin_amdgcn_s_setprio(0);                                          \
    } while (0)

__global__ __launch_bounds__(512, 2) void gemm256_4ph(
    const __hip_bfloat16* __restrict__ A,
    const __hip_bfloat16* __restrict__ Bt,
    __hip_bfloat16* __restrict__ C,
    int M, int N, int K)
{
    __shared__ __align__(16) __hip_bfloat16 As[2][2][128 * 64];   // 64 KiB
    __shared__ __align__(16) __hip_bfloat16 Bs[2][2][128 * 64];   // 64 KiB

    const int tid  = threadIdx.x;
    const int lane = tid & 63;
    const int wv   = tid >> 6;
    const int wq2  = wv >> 2;       // 0..1: 64-row slice within a 128-row A-half
    const int wq4  = wv & 3;        // 0..3: 32-col slice within a 128-col B-half

    // bijective XCD swizzle (gridDim.x % 8 == 0)
    const int nwg = gridDim.x;
    const int cpx = nwg >> 3;
    const int bid = blockIdx.x;
    const int swb = (bid & 7) * cpx + (bid >> 3);
    const int nbn = N >> 8;
    const int bm = swb / nbn, bn = swb % nbn;

    const int NT = K >> 6;          // K-tiles of 64

    const __hip_bfloat16* Ag = A  + (size_t)(bm << 8) * K;
    const __hip_bfloat16* Bg = Bt + (size_t)(bn << 8) * K;

    // fragment lane geometry
    const int fm = lane & 15;
    const int fu = lane >> 4;       // 0..3: 16B unit within a 32-elem k-half

    f32x4 acc[2][2][4][2] = {};
    bf16x8 a[4][2], b0[2][2], b1[2][2];

    // ---- prologue: 7 stage-groups in stream order; certify {Ah0,Bh0}(0) ----
    STAGEH(Ag, &As[0][0][0], 0, 0);   // G0 Ah0(t0)
    STAGEH(Bg, &Bs[0][0][0], 0, 0);   // G1 Bh0(t0)
    STAGEH(Bg, &Bs[0][1][0], 0, 1);   // G2 Bh1(t0)
    STAGEH(Ag, &As[0][1][0], 0, 1);   // G3 Ah1(t0)
    STAGEH(Ag, &As[1][0][0], 1, 0);   // G4 Ah0(t1)
    STAGEH(Bg, &Bs[1][0][0], 1, 0);   // G5 Bh0(t1)
    STAGEH(Bg, &Bs[1][1][0], 1, 1);   // G6 Bh1(t1)
    VM10();                           // drains G0,G1 for every wave
    BAR();

    for (int t = 0; t < NT; ++t) {
        const int cur = t & 1, nxt = cur ^ 1;
        int t1 = t + 1; if (t1 >= NT) t1 -= NT;   // wrapped: staged, never read
        int t2 = t + 2; if (t2 >= NT) t2 -= NT;

        // ph0: Q(0,0). reads certified @ ph3(t-1) / prologue.
        READ_A(cur, 0);
        READ_B(cur, 0, b0);
        STAGEH(Ag, &As[nxt][1][0], t1, 1);         // Ah1(t+1): dead since ph2(t-1)
        BAR(); LGKM0_SB();
        MFMA16(0, 0, b0);
        VM10();                                    // certifies Bh1(t)
        BAR();

        // ph1: Q(0,1) (reuse a)
        READ_B(cur, 1, b1);
        STAGEH(Ag, &As[cur][0][0], t2, 0);         // Ah0(t+2): dead since ph0(t)
        BAR(); LGKM0_SB();
        MFMA16(0, 1, b1);
        VM10();                                    // certifies Ah1(t)
        BAR();

        // ph2: Q(1,0) (reuse b0; a overwritten)
        READ_A(cur, 1);
        STAGEH(Bg, &Bs[cur][0][0], t2, 0);         // Bh0(t+2): dead since ph0(t)
        BAR(); LGKM0_SB();
        MFMA16(1, 0, b0);
        BAR();

        // ph3: Q(1,1) (regs only)
        STAGEH(Bg, &Bs[cur][1][0], t2, 1);         // Bh1(t+2): dead since ph1(t)
        MFMA16(1, 1, b1);
        VM10();                                    // certifies {Ah0,Bh0}(t+1)
        BAR();
    }
    asm volatile("s_waitcnt vmcnt(0)" ::: "memory");   // drain wrapped stages

    // C/D layout: col=lane&15, row=(lane>>4)*4+reg  [m89-verified]
    const int fcol  = lane & 15;
    const int frow4 = (lane >> 4) << 2;
#pragma unroll
    for (int qi = 0; qi < 2; ++qi)
#pragma unroll
        for (int qj = 0; qj < 2; ++qj)
#pragma unroll
            for (int j = 0; j < 2; ++j) {
                int col = (bn << 8) + qj * 128 + wq4 * 32 + j * 16 + fcol;
#pragma unroll
                for (int i = 0; i < 4; ++i)
#pragma unroll
                    for (int r = 0; r < 4; ++r) {
                        int row = (bm << 8) + qi * 128 + wq2 * 64 + i * 16 + frow4 + r;
                        C[(size_t)row * N + col] = __hip_bfloat16(acc[qi][qj][i][j][r]);
                    }
            }
}

// -------- GEMM2: 64x128 tile, BK=64 (512 blocks = 2/CU), fp32 out + bias --------
__global__ __launch_bounds__(256) void gemm_bt_64(
    const __hip_bfloat16* __restrict__ A,
    const __hip_bfloat16* __restrict__ Bt,
    const float* __restrict__ bias,
    float* __restrict__ C,
    int M, int N, int K)
{
    __shared__ __align__(16) __hip_bfloat16 As2[2 * 64 * 32];
    __shared__ __align__(16) __hip_bfloat16 Bs2[2 * 128 * 32];

    const int tid  = threadIdx.x;
    const int wv   = tid >> 6;
    const int lane = tid & 63;
    const int bn   = blockIdx.x, bm = blockIdx.y;
    const int wm   = wv >> 1, wn = wv & 1;

    f32x4 acc[2][4] = {};

    const int srow = lane >> 2;
    const int scol = (lane & 3) * 8;

    const __hip_bfloat16* Ag = A  + (size_t)(bm * 64) * K;
    const __hip_bfloat16* Bg = Bt + (size_t)(bn * 128) * K;

    const int fm = lane & 15;
    const int fq = (lane >> 4) * 8;

    for (int kk = 0; kk < K; kk += 64) {
#pragma unroll
        for (int kh = 0; kh < 2; ++kh) {
            {
                int row = wv * 16 + srow;                     // 0..63
                gld_lds16(Ag + (size_t)row * K + kk + kh * 32 + scol,
                          As2 + kh * 2048 + row * 32 + scol);
            }
#pragma unroll
            for (int it = 0; it < 2; ++it) {
                int row = (it * 4 + wv) * 16 + srow;          // 0..127
                gld_lds16(Bg + (size_t)row * K + kk + kh * 32 + scol,
                          Bs2 + kh * 4096 + row * 32 + scol);
            }
        }
        __syncthreads();

#pragma unroll
        for (int kh = 0; kh < 2; ++kh) {
            bf16x8 af[2], bfr[4];
#pragma unroll
            for (int i = 0; i < 2; ++i)
                af[i] = *(const bf16x8*)(As2 + kh * 2048 + (wm * 32 + i * 16 + fm) * 32 + fq);
#pragma unroll
            for (int j = 0; j < 4; ++j)
                bfr[j] = *(const bf16x8*)(Bs2 + kh * 4096 + (wn * 64 + j * 16 + fm) * 32 + fq);
#pragma unroll
            for (int i = 0; i < 2; ++i)
#pragma unroll
                for (int j = 0; j < 4; ++j)
                    acc[i][j] = __builtin_amdgcn_mfma_f32_16x16x32_bf16(af[i], bfr[j], acc[i][j], 0, 0, 0);
        }
        __syncthreads();
    }

    const int fcol  = lane & 15;
    const int frow4 = (lane >> 4) * 4;
    const int cm0 = bm * 64 + wm * 32;
    const int cn0 = bn * 128 + wn * 64;
#pragma unroll
    for (int j = 0; j < 4; ++j) {
        int col = cn0 + j * 16 + fcol;
        float bv = bias[col];
#pragma unroll
        for (int i = 0; i < 2; ++i)
#pragma unroll
            for (int r = 0; r < 4; ++r) {
                int row = cm0 + i * 16 + frow4 + r;
                C[(size_t)row * N + col] = acc[i][j][r] + bv;
            }
    }
}

// -------- banded attention, vectorized: one block per token, thread = 4-dim chunk --------
__global__ __launch_bounds__(256) void attn_banded(
    const __hip_bfloat16* __restrict__ qkv,   // (B*T, 3*DIM): [q | k | v]
    __hip_bfloat16* __restrict__ o)           // (B*T, DIM)
{
    const int t4 = threadIdx.x;          // dim-chunk index: dims [4*t4, 4*t4+4)
    const int r  = blockIdx.x;           // b*T + t
    const int t  = r & (T_SEQ - 1);
    const size_t rb = (size_t)r * (3 * DIMSZ);
    const int d0 = t4 * 4;

    ushort4 qu = *(const ushort4*)(qkv + rb + d0);
    float q0 = bf2f(qu.x), q1 = bf2f(qu.y), q2 = bf2f(qu.z), q3 = bf2f(qu.w);

    float s[3], vvx[3], vvy[3], vvz[3], vvw[3];
#pragma unroll
    for (int j = 0; j < 3; ++j) {
        bool ok = (t + j) < T_SEQ;       // masks seq end (and batch boundary)
        size_t rbj = ok ? rb + (size_t)j * (3 * DIMSZ) : rb;
        ushort4 ku = *(const ushort4*)(qkv + rbj + DIMSZ + d0);
        ushort4 vu = *(const ushort4*)(qkv + rbj + 2 * DIMSZ + d0);
        vvx[j] = bf2f(vu.x); vvy[j] = bf2f(vu.y); vvz[j] = bf2f(vu.z); vvw[j] = bf2f(vu.w);
        float d = q0 * bf2f(ku.x) + q1 * bf2f(ku.y) + q2 * bf2f(ku.z) + q3 * bf2f(ku.w);
#pragma unroll
        for (int off = 8; off > 0; off >>= 1)
            d += __shfl_xor(d, off, 64); // reduce within 16-lane head group
        s[j] = ok ? d * 0.125f : -1e30f; // scale = 64^-0.5
    }
    float m  = fmaxf(s[0], fmaxf(s[1], s[2]));
    float p0 = __expf(s[0] - m), p1 = __expf(s[1] - m), p2 = __expf(s[2] - m);
    float inv = 1.0f / (p0 + p1 + p2);
    union { __hip_bfloat16 h[4]; ushort4 uu; } pk;
    pk.h[0] = __hip_bfloat16((p0 * vvx[0] + p1 * vvx[1] + p2 * vvx[2]) * inv);
    pk.h[1] = __hip_bfloat16((p0 * vvy[0] + p1 * vvy[1] + p2 * vvy[2]) * inv);
    pk.h[2] = __hip_bfloat16((p0 * vvz[0] + p1 * vvz[1] + p2 * vvz[2]) * inv);
    pk.h[3] = __hip_bfloat16((p0 * vvw[0] + p1 * vvw[1] + p2 * vvw[2]) * inv);
    *(ushort4*)(o + (size_t)r * DIMSZ + d0) = pk.uu;
}

extern "C" void kernel_launch(void* const* d_in, const int* in_sizes, int n_in,
                              void* d_out, int out_size, void* d_ws, size_t ws_size,
                              hipStream_t stream) {
    const float* x      = (const float*)d_in[0];  // (B,T,DIM) fp32
    const float* w_qkv  = (const float*)d_in[1];  // (DIM, 3*DIM) fp32
    const float* w_proj = (const float*)d_in[2];  // (DIM, DIM) fp32
    const float* b_proj = (const float*)d_in[3];  // (DIM,) fp32
    float* out = (float*)d_out;                   // (B,T,DIM) fp32

    const int M = NBATCH * T_SEQ;   // 4096

    // workspace (bf16 intermediates):
    //   [0,8M)    xb (x bf16) -> reused as attn output after GEMM1 consumes it
    //   [8M,14M)  wqkvT  (3072x1024)
    //   [14M,16M) wprojT (1024x1024)
    //   [16M,40M) qkv    (4096x3072)
    char* ws = (char*)d_ws;
    __hip_bfloat16* xb     = (__hip_bfloat16*)(ws);
    __hip_bfloat16* attn   = (__hip_bfloat16*)(ws);            // reuse of xb region
    __hip_bfloat16* wqkvT  = (__hip_bfloat16*)(ws + (8u  << 20));
    __hip_bfloat16* wprojT = (__hip_bfloat16*)(ws + (14u << 20));
    __hip_bfloat16* qkv    = (__hip_bfloat16*)(ws + (16u << 20));

    // 1) fused prep: x->bf16, both weight convert+transposes
    prep<<<8192, 256, 0, stream>>>(x, xb, w_qkv, wqkvT, w_proj, wprojT);

    // 2) qkv = x @ w_qkv (4096 x 3072, K=1024): 16x12 = 192 blocks, 512 thr, 1/CU
    gemm256_4ph<<<dim3((M / 256) * (3 * DIMSZ / 256)), 512, 0, stream>>>(
        xb, wqkvT, qkv, M, 3 * DIMSZ, DIMSZ);

    // 3) banded attention (3-key window) -> bf16 attn (reuses xb region)
    attn_banded<<<M, 256, 0, stream>>>(qkv, attn);

    // 4) out = attn @ w_proj + b_proj  (4096 x 1024): 8x64=512 blocks = 2/CU
    gemm_bt_64<<<dim3(DIMSZ / 128, M / 64), 256, 0, stream>>>(
        attn, wprojT, b_proj, out, M, DIMSZ, DIMSZ);
}

// Round 5
// 143.198 us; speedup vs baseline: 1.0994x; 1.0487x over previous
//
#include <hip/hip_runtime.h>
#include <hip/hip_bf16.h>
#include <cstdint>
#include <cstddef>

// StreamingAttentionBlock: B=2, T=2048, DIM=1024, H=16, hd=64, window=3 keys
// I/O: fp32. Internal: bf16 MFMA, fp32 accumulation.
// R14: GEMM1 reverted to known-good gemm_bt_128 (35.4us measured; the 4-phase
// 256^2 port peaked at 41.8us: 192 blocks = 75% CU occupancy + short K).
// New this round (residual attack; residual = const 108.4us across R0/R11/R13):
//   - prep: weight transpose in 64x64 tiles, float tile[64][65]: read 256B/wave,
//     write 128B/wave (was 64B), LDS bank pattern (ox+oy)%32 = 2-way (free).
//   - attn: 2 tokens/block, bf16x8 16B loads/stores (was 8B), 3-step 8-lane
//     shuffle reduce (head = 8 lanes x 8 dims) instead of 4-step 16-lane.
// Budget note: timed iteration appears to include the harness's 256MiB ws
// re-poison fill (~43.5us, WRITE_SIZE=262144KB) — unoptimizable; kernel-side
// budget is ~65us across prep/attn/gemm2 + 35.4 GEMM1.
#define T_SEQ 2048
#define NBATCH 2
#define DIMSZ 1024
#define NHEAD 16
#define HDIM 64

typedef float f32x4 __attribute__((ext_vector_type(4)));
typedef short bf16x8 __attribute__((ext_vector_type(8)));

// async global->LDS, 16B per lane. LDS dest = wave-uniform base + lane*16.
__device__ __forceinline__ void gld_lds16(const __hip_bfloat16* g, __hip_bfloat16* l) {
    __builtin_amdgcn_global_load_lds(
        (const __attribute__((address_space(1))) unsigned int*)g,
        (__attribute__((address_space(3))) unsigned int*)l,
        16, 0, 0);
}

__device__ __forceinline__ float bf2f(unsigned short u) {
    union { unsigned int i; float f; } c; c.i = (unsigned int)u << 16; return c.f;
}

// -------- fused prep: convert x -> bf16; convert+transpose both weights --------
// grid: [0,4096) x-convert | [4096,4864) wqkv 64x64 tiles | [4864,5120) wproj
__global__ __launch_bounds__(256) void prep(
    const float* __restrict__ x,      __hip_bfloat16* __restrict__ xb,
    const float* __restrict__ wqkv,   __hip_bfloat16* __restrict__ wqkvT,
    const float* __restrict__ wproj,  __hip_bfloat16* __restrict__ wprojT)
{
    __shared__ float tile[64][65];
    const int b = blockIdx.x;
    if (b < 4096) {
        int i = (b * 256 + threadIdx.x) * 4;
        float4 v = *(const float4*)(x + i);
        union { __hip_bfloat16 h[4]; ushort4 u; } pk;
        pk.h[0] = __hip_bfloat16(v.x); pk.h[1] = __hip_bfloat16(v.y);
        pk.h[2] = __hip_bfloat16(v.z); pk.h[3] = __hip_bfloat16(v.w);
        *(ushort4*)(xb + i) = pk.u;
        return;
    }
    const float* in; __hip_bfloat16* out; int C, c0, r0;
    if (b < 4864) {
        int bb = b - 4096; in = wqkv; out = wqkvT; C = 3072;
        c0 = (bb % 48) * 64; r0 = (bb / 48) * 64;
    } else {
        int bb = b - 4864; in = wproj; out = wprojT; C = 1024;
        c0 = (bb & 15) * 64; r0 = (bb >> 4) * 64;
    }
    const int tx = threadIdx.x & 63, ty = threadIdx.x >> 6;   // 64 lanes x 4 rows
#pragma unroll
    for (int p = 0; p < 16; ++p) {
        int row = ty + p * 4;
        tile[row][tx] = in[(size_t)(r0 + row) * C + c0 + tx];
    }
    __syncthreads();
#pragma unroll
    for (int p = 0; p < 16; ++p) {
        int orow = ty + p * 4;   // out row = c0+orow; out col = r0+tx
        out[(size_t)(c0 + orow) * 1024 + r0 + tx] = __hip_bfloat16(tile[tx][orow]);
    }
}

// -------- GEMM1: 128x128 tile, BK=64 as two m97-style 32-wide sub-tiles --------
__global__ __launch_bounds__(256) void gemm_bt_128(
    const __hip_bfloat16* __restrict__ A,
    const __hip_bfloat16* __restrict__ Bt,
    __hip_bfloat16* __restrict__ C,
    int M, int N, int K)
{
    __shared__ __align__(16) __hip_bfloat16 As[2 * 128 * 32];
    __shared__ __align__(16) __hip_bfloat16 Bs[2 * 128 * 32];

    const int tid  = threadIdx.x;
    const int wv   = tid >> 6;
    const int lane = tid & 63;
    const int bn   = blockIdx.x, bm = blockIdx.y;
    const int wm   = wv >> 1, wn = wv & 1;

    f32x4 acc[4][4] = {};

    const int srow = lane >> 2;          // 0..15
    const int scol = (lane & 3) * 8;     // 16B per lane

    const __hip_bfloat16* Ag = A  + (size_t)(bm * 128) * K;
    const __hip_bfloat16* Bg = Bt + (size_t)(bn * 128) * K;

    const int fm = lane & 15;
    const int fq = (lane >> 4) * 8;

    for (int kk = 0; kk < K; kk += 64) {
#pragma unroll
        for (int kh = 0; kh < 2; ++kh)
#pragma unroll
            for (int it = 0; it < 2; ++it) {
                int row = (it * 4 + wv) * 16 + srow;          // 0..127
                gld_lds16(Ag + (size_t)row * K + kk + kh * 32 + scol,
                          As + kh * 4096 + row * 32 + scol);
                gld_lds16(Bg + (size_t)row * K + kk + kh * 32 + scol,
                          Bs + kh * 4096 + row * 32 + scol);
            }
        __syncthreads();

#pragma unroll
        for (int kh = 0; kh < 2; ++kh) {
            bf16x8 af[4], bfr[4];
#pragma unroll
            for (int i = 0; i < 4; ++i)
                af[i] = *(const bf16x8*)(As + kh * 4096 + (wm * 64 + i * 16 + fm) * 32 + fq);
#pragma unroll
            for (int j = 0; j < 4; ++j)
                bfr[j] = *(const bf16x8*)(Bs + kh * 4096 + (wn * 64 + j * 16 + fm) * 32 + fq);
#pragma unroll
            for (int i = 0; i < 4; ++i)
#pragma unroll
                for (int j = 0; j < 4; ++j)
                    acc[i][j] = __builtin_amdgcn_mfma_f32_16x16x32_bf16(af[i], bfr[j], acc[i][j], 0, 0, 0);
        }
        __syncthreads();
    }

    // C/D layout: col=lane&15, row=(lane>>4)*4+reg  [m89-verified]
    const int fcol  = lane & 15;
    const int frow4 = (lane >> 4) * 4;
    const int cm0 = bm * 128 + wm * 64;
    const int cn0 = bn * 128 + wn * 64;
#pragma unroll
    for (int j = 0; j < 4; ++j) {
        int col = cn0 + j * 16 + fcol;
#pragma unroll
        for (int i = 0; i < 4; ++i)
#pragma unroll
            for (int r = 0; r < 4; ++r) {
                int row = cm0 + i * 16 + frow4 + r;
                C[(size_t)row * N + col] = __hip_bfloat16(acc[i][j][r]);
            }
    }
}

// -------- GEMM2: 64x128 tile, BK=64 (512 blocks = 2/CU), fp32 out + bias --------
__global__ __launch_bounds__(256) void gemm_bt_64(
    const __hip_bfloat16* __restrict__ A,
    const __hip_bfloat16* __restrict__ Bt,
    const float* __restrict__ bias,
    float* __restrict__ C,
    int M, int N, int K)
{
    __shared__ __align__(16) __hip_bfloat16 As2[2 * 64 * 32];
    __shared__ __align__(16) __hip_bfloat16 Bs2[2 * 128 * 32];

    const int tid  = threadIdx.x;
    const int wv   = tid >> 6;
    const int lane = tid & 63;
    const int bn   = blockIdx.x, bm = blockIdx.y;
    const int wm   = wv >> 1, wn = wv & 1;

    f32x4 acc[2][4] = {};

    const int srow = lane >> 2;
    const int scol = (lane & 3) * 8;

    const __hip_bfloat16* Ag = A  + (size_t)(bm * 64) * K;
    const __hip_bfloat16* Bg = Bt + (size_t)(bn * 128) * K;

    const int fm = lane & 15;
    const int fq = (lane >> 4) * 8;

    for (int kk = 0; kk < K; kk += 64) {
#pragma unroll
        for (int kh = 0; kh < 2; ++kh) {
            {
                int row = wv * 16 + srow;                     // 0..63
                gld_lds16(Ag + (size_t)row * K + kk + kh * 32 + scol,
                          As2 + kh * 2048 + row * 32 + scol);
            }
#pragma unroll
            for (int it = 0; it < 2; ++it) {
                int row = (it * 4 + wv) * 16 + srow;          // 0..127
                gld_lds16(Bg + (size_t)row * K + kk + kh * 32 + scol,
                          Bs2 + kh * 4096 + row * 32 + scol);
            }
        }
        __syncthreads();

#pragma unroll
        for (int kh = 0; kh < 2; ++kh) {
            bf16x8 af[2], bfr[4];
#pragma unroll
            for (int i = 0; i < 2; ++i)
                af[i] = *(const bf16x8*)(As2 + kh * 2048 + (wm * 32 + i * 16 + fm) * 32 + fq);
#pragma unroll
            for (int j = 0; j < 4; ++j)
                bfr[j] = *(const bf16x8*)(Bs2 + kh * 4096 + (wn * 64 + j * 16 + fm) * 32 + fq);
#pragma unroll
            for (int i = 0; i < 2; ++i)
#pragma unroll
                for (int j = 0; j < 4; ++j)
                    acc[i][j] = __builtin_amdgcn_mfma_f32_16x16x32_bf16(af[i], bfr[j], acc[i][j], 0, 0, 0);
        }
        __syncthreads();
    }

    const int fcol  = lane & 15;
    const int frow4 = (lane >> 4) * 4;
    const int cm0 = bm * 64 + wm * 32;
    const int cn0 = bn * 128 + wn * 64;
#pragma unroll
    for (int j = 0; j < 4; ++j) {
        int col = cn0 + j * 16 + fcol;
        float bv = bias[col];
#pragma unroll
        for (int i = 0; i < 2; ++i)
#pragma unroll
            for (int r = 0; r < 4; ++r) {
                int row = cm0 + i * 16 + frow4 + r;
                C[(size_t)row * N + col] = acc[i][j][r] + bv;
            }
    }
}

// -------- banded attention: 2 tokens/block, thread = 8-dim chunk, 16B loads --------
__global__ __launch_bounds__(256) void attn_banded(
    const __hip_bfloat16* __restrict__ qkv,   // (B*T, 3*DIM): [q | k | v]
    __hip_bfloat16* __restrict__ o)           // (B*T, DIM)
{
    const int tid = threadIdx.x;
    const int t8  = tid & 127;           // dim-chunk: dims [8*t8, 8*t8+8)
    const int r   = blockIdx.x * 2 + (tid >> 7);   // b*T + t
    const int t   = r & (T_SEQ - 1);
    const size_t rb = (size_t)r * (3 * DIMSZ);
    const int d0 = t8 * 8;

    bf16x8 qu = *(const bf16x8*)(qkv + rb + d0);
    float q[8];
#pragma unroll
    for (int i = 0; i < 8; ++i) q[i] = bf2f((unsigned short)qu[i]);

    float s[3], vv[3][8];
#pragma unroll
    for (int j = 0; j < 3; ++j) {
        bool ok = (t + j) < T_SEQ;       // masks seq end (and batch boundary)
        size_t rbj = ok ? rb + (size_t)j * (3 * DIMSZ) : rb;
        bf16x8 ku = *(const bf16x8*)(qkv + rbj + DIMSZ + d0);
        bf16x8 vu = *(const bf16x8*)(qkv + rbj + 2 * DIMSZ + d0);
        float d = 0.f;
#pragma unroll
        for (int i = 0; i < 8; ++i) {
            vv[j][i] = bf2f((unsigned short)vu[i]);
            d += q[i] * bf2f((unsigned short)ku[i]);
        }
        // head = 64 dims = 8 lanes x 8 dims: reduce within aligned 8-lane group
        d += __shfl_xor(d, 4, 64);
        d += __shfl_xor(d, 2, 64);
        d += __shfl_xor(d, 1, 64);
        s[j] = ok ? d * 0.125f : -1e30f; // scale = 64^-0.5
    }
    float m  = fmaxf(s[0], fmaxf(s[1], s[2]));
    float p0 = __expf(s[0] - m), p1 = __expf(s[1] - m), p2 = __expf(s[2] - m);
    float inv = 1.0f / (p0 + p1 + p2);
    union { __hip_bfloat16 h[8]; bf16x8 u; } pk;
#pragma unroll
    for (int i = 0; i < 8; ++i)
        pk.h[i] = __hip_bfloat16((p0 * vv[0][i] + p1 * vv[1][i] + p2 * vv[2][i]) * inv);
    *(bf16x8*)(o + (size_t)r * DIMSZ + d0) = pk.u;
}

extern "C" void kernel_launch(void* const* d_in, const int* in_sizes, int n_in,
                              void* d_out, int out_size, void* d_ws, size_t ws_size,
                              hipStream_t stream) {
    const float* x      = (const float*)d_in[0];  // (B,T,DIM) fp32
    const float* w_qkv  = (const float*)d_in[1];  // (DIM, 3*DIM) fp32
    const float* w_proj = (const float*)d_in[2];  // (DIM, DIM) fp32
    const float* b_proj = (const float*)d_in[3];  // (DIM,) fp32
    float* out = (float*)d_out;                   // (B,T,DIM) fp32

    const int M = NBATCH * T_SEQ;   // 4096

    // workspace (bf16 intermediates):
    //   [0,8M)    xb (x bf16) -> reused as attn output after GEMM1 consumes it
    //   [8M,14M)  wqkvT  (3072x1024)
    //   [14M,16M) wprojT (1024x1024)
    //   [16M,40M) qkv    (4096x3072)
    char* ws = (char*)d_ws;
    __hip_bfloat16* xb     = (__hip_bfloat16*)(ws);
    __hip_bfloat16* attn   = (__hip_bfloat16*)(ws);            // reuse of xb region
    __hip_bfloat16* wqkvT  = (__hip_bfloat16*)(ws + (8u  << 20));
    __hip_bfloat16* wprojT = (__hip_bfloat16*)(ws + (14u << 20));
    __hip_bfloat16* qkv    = (__hip_bfloat16*)(ws + (16u << 20));

    // 1) fused prep: x->bf16, both weight convert+transposes (64x64 tiles)
    prep<<<5120, 256, 0, stream>>>(x, xb, w_qkv, wqkvT, w_proj, wprojT);

    // 2) qkv = x @ w_qkv   (4096 x 3072, K=1024): 24x32=768 blocks = 3/CU
    gemm_bt_128<<<dim3(3 * DIMSZ / 128, M / 128), 256, 0, stream>>>(
        xb, wqkvT, qkv, M, 3 * DIMSZ, DIMSZ);

    // 3) banded attention (3-key window) -> bf16 attn (reuses xb region)
    attn_banded<<<M / 2, 256, 0, stream>>>(qkv, attn);

    // 4) out = attn @ w_proj + b_proj  (4096 x 1024): 8x64=512 blocks = 2/CU
    gemm_bt_64<<<dim3(DIMSZ / 128, M / 64), 256, 0, stream>>>(
        attn, wprojT, b_proj, out, M, DIMSZ, DIMSZ);
}

// Round 6
// 141.413 us; speedup vs baseline: 1.1133x; 1.0126x over previous
//
#include <hip/hip_runtime.h>
#include <hip/hip_bf16.h>
#include <cstdint>
#include <cstddef>

// StreamingAttentionBlock: B=2, T=2048, DIM=1024, H=16, hd=64, window=3 keys
// I/O: fp32. Internal: bf16 MFMA, fp32 accumulation.
// R15: GEMM2 BK=64 -> BK=128 (4 sub-tiles per barrier pair: 12 DMA issues,
// 64 MFMA per drain instead of 6/16). Halves the per-K-step vmcnt(0)+barrier
// drain count (the m97-structure's dominant stall) while LDS 24->48 KB keeps
// occupancy at exactly 2 blocks/CU (m132's BK=128 regression was an occupancy
// drop, absent here). GEMM1/prep/attn unchanged (measured floor).
// Budget (R14 evidence): total 143.2 = fill 43.5 + GEMM1 35.4 + prep ~11 +
// attn ~10 + gaps ~8 + GEMM2 ~19-22 <- this round's target.
#define T_SEQ 2048
#define NBATCH 2
#define DIMSZ 1024
#define NHEAD 16
#define HDIM 64

typedef float f32x4 __attribute__((ext_vector_type(4)));
typedef short bf16x8 __attribute__((ext_vector_type(8)));

// async global->LDS, 16B per lane. LDS dest = wave-uniform base + lane*16.
__device__ __forceinline__ void gld_lds16(const __hip_bfloat16* g, __hip_bfloat16* l) {
    __builtin_amdgcn_global_load_lds(
        (const __attribute__((address_space(1))) unsigned int*)g,
        (__attribute__((address_space(3))) unsigned int*)l,
        16, 0, 0);
}

__device__ __forceinline__ float bf2f(unsigned short u) {
    union { unsigned int i; float f; } c; c.i = (unsigned int)u << 16; return c.f;
}

// -------- fused prep: convert x -> bf16; convert+transpose both weights --------
// grid: [0,4096) x-convert | [4096,4864) wqkv 64x64 tiles | [4864,5120) wproj
__global__ __launch_bounds__(256) void prep(
    const float* __restrict__ x,      __hip_bfloat16* __restrict__ xb,
    const float* __restrict__ wqkv,   __hip_bfloat16* __restrict__ wqkvT,
    const float* __restrict__ wproj,  __hip_bfloat16* __restrict__ wprojT)
{
    __shared__ float tile[64][65];
    const int b = blockIdx.x;
    if (b < 4096) {
        int i = (b * 256 + threadIdx.x) * 4;
        float4 v = *(const float4*)(x + i);
        union { __hip_bfloat16 h[4]; ushort4 u; } pk;
        pk.h[0] = __hip_bfloat16(v.x); pk.h[1] = __hip_bfloat16(v.y);
        pk.h[2] = __hip_bfloat16(v.z); pk.h[3] = __hip_bfloat16(v.w);
        *(ushort4*)(xb + i) = pk.u;
        return;
    }
    const float* in; __hip_bfloat16* out; int C, c0, r0;
    if (b < 4864) {
        int bb = b - 4096; in = wqkv; out = wqkvT; C = 3072;
        c0 = (bb % 48) * 64; r0 = (bb / 48) * 64;
    } else {
        int bb = b - 4864; in = wproj; out = wprojT; C = 1024;
        c0 = (bb & 15) * 64; r0 = (bb >> 4) * 64;
    }
    const int tx = threadIdx.x & 63, ty = threadIdx.x >> 6;   // 64 lanes x 4 rows
#pragma unroll
    for (int p = 0; p < 16; ++p) {
        int row = ty + p * 4;
        tile[row][tx] = in[(size_t)(r0 + row) * C + c0 + tx];
    }
    __syncthreads();
#pragma unroll
    for (int p = 0; p < 16; ++p) {
        int orow = ty + p * 4;   // out row = c0+orow; out col = r0+tx
        out[(size_t)(c0 + orow) * 1024 + r0 + tx] = __hip_bfloat16(tile[tx][orow]);
    }
}

// -------- GEMM1: 128x128 tile, BK=64 as two m97-style 32-wide sub-tiles --------
__global__ __launch_bounds__(256) void gemm_bt_128(
    const __hip_bfloat16* __restrict__ A,
    const __hip_bfloat16* __restrict__ Bt,
    __hip_bfloat16* __restrict__ C,
    int M, int N, int K)
{
    __shared__ __align__(16) __hip_bfloat16 As[2 * 128 * 32];
    __shared__ __align__(16) __hip_bfloat16 Bs[2 * 128 * 32];

    const int tid  = threadIdx.x;
    const int wv   = tid >> 6;
    const int lane = tid & 63;
    const int bn   = blockIdx.x, bm = blockIdx.y;
    const int wm   = wv >> 1, wn = wv & 1;

    f32x4 acc[4][4] = {};

    const int srow = lane >> 2;          // 0..15
    const int scol = (lane & 3) * 8;     // 16B per lane

    const __hip_bfloat16* Ag = A  + (size_t)(bm * 128) * K;
    const __hip_bfloat16* Bg = Bt + (size_t)(bn * 128) * K;

    const int fm = lane & 15;
    const int fq = (lane >> 4) * 8;

    for (int kk = 0; kk < K; kk += 64) {
#pragma unroll
        for (int kh = 0; kh < 2; ++kh)
#pragma unroll
            for (int it = 0; it < 2; ++it) {
                int row = (it * 4 + wv) * 16 + srow;          // 0..127
                gld_lds16(Ag + (size_t)row * K + kk + kh * 32 + scol,
                          As + kh * 4096 + row * 32 + scol);
                gld_lds16(Bg + (size_t)row * K + kk + kh * 32 + scol,
                          Bs + kh * 4096 + row * 32 + scol);
            }
        __syncthreads();

#pragma unroll
        for (int kh = 0; kh < 2; ++kh) {
            bf16x8 af[4], bfr[4];
#pragma unroll
            for (int i = 0; i < 4; ++i)
                af[i] = *(const bf16x8*)(As + kh * 4096 + (wm * 64 + i * 16 + fm) * 32 + fq);
#pragma unroll
            for (int j = 0; j < 4; ++j)
                bfr[j] = *(const bf16x8*)(Bs + kh * 4096 + (wn * 64 + j * 16 + fm) * 32 + fq);
#pragma unroll
            for (int i = 0; i < 4; ++i)
#pragma unroll
                for (int j = 0; j < 4; ++j)
                    acc[i][j] = __builtin_amdgcn_mfma_f32_16x16x32_bf16(af[i], bfr[j], acc[i][j], 0, 0, 0);
        }
        __syncthreads();
    }

    // C/D layout: col=lane&15, row=(lane>>4)*4+reg  [m89-verified]
    const int fcol  = lane & 15;
    const int frow4 = (lane >> 4) * 4;
    const int cm0 = bm * 128 + wm * 64;
    const int cn0 = bn * 128 + wn * 64;
#pragma unroll
    for (int j = 0; j < 4; ++j) {
        int col = cn0 + j * 16 + fcol;
#pragma unroll
        for (int i = 0; i < 4; ++i)
#pragma unroll
            for (int r = 0; r < 4; ++r) {
                int row = cm0 + i * 16 + frow4 + r;
                C[(size_t)row * N + col] = __hip_bfloat16(acc[i][j][r]);
            }
    }
}

// -------- GEMM2: 64x128 tile, BK=128 (4 sub-tiles / barrier pair), fp32+bias --------
__global__ __launch_bounds__(256, 2) void gemm_bt_64(
    const __hip_bfloat16* __restrict__ A,
    const __hip_bfloat16* __restrict__ Bt,
    const float* __restrict__ bias,
    float* __restrict__ C,
    int M, int N, int K)
{
    __shared__ __align__(16) __hip_bfloat16 As2[4 * 64 * 32];    // 16 KiB
    __shared__ __align__(16) __hip_bfloat16 Bs2[4 * 128 * 32];   // 32 KiB

    const int tid  = threadIdx.x;
    const int wv   = tid >> 6;
    const int lane = tid & 63;
    const int bn   = blockIdx.x, bm = blockIdx.y;
    const int wm   = wv >> 1, wn = wv & 1;

    f32x4 acc[2][4] = {};

    const int srow = lane >> 2;
    const int scol = (lane & 3) * 8;

    const __hip_bfloat16* Ag = A  + (size_t)(bm * 64) * K;
    const __hip_bfloat16* Bg = Bt + (size_t)(bn * 128) * K;

    const int fm = lane & 15;
    const int fq = (lane >> 4) * 8;

    for (int kk = 0; kk < K; kk += 128) {
#pragma unroll
        for (int kh = 0; kh < 4; ++kh) {
            {
                int row = wv * 16 + srow;                     // 0..63
                gld_lds16(Ag + (size_t)row * K + kk + kh * 32 + scol,
                          As2 + kh * 2048 + row * 32 + scol);
            }
#pragma unroll
            for (int it = 0; it < 2; ++it) {
                int row = (it * 4 + wv) * 16 + srow;          // 0..127
                gld_lds16(Bg + (size_t)row * K + kk + kh * 32 + scol,
                          Bs2 + kh * 4096 + row * 32 + scol);
            }
        }
        __syncthreads();

#pragma unroll
        for (int kh = 0; kh < 4; ++kh) {
            bf16x8 af[2], bfr[4];
#pragma unroll
            for (int i = 0; i < 2; ++i)
                af[i] = *(const bf16x8*)(As2 + kh * 2048 + (wm * 32 + i * 16 + fm) * 32 + fq);
#pragma unroll
            for (int j = 0; j < 4; ++j)
                bfr[j] = *(const bf16x8*)(Bs2 + kh * 4096 + (wn * 64 + j * 16 + fm) * 32 + fq);
#pragma unroll
            for (int i = 0; i < 2; ++i)
#pragma unroll
                for (int j = 0; j < 4; ++j)
                    acc[i][j] = __builtin_amdgcn_mfma_f32_16x16x32_bf16(af[i], bfr[j], acc[i][j], 0, 0, 0);
        }
        __syncthreads();
    }

    const int fcol  = lane & 15;
    const int frow4 = (lane >> 4) * 4;
    const int cm0 = bm * 64 + wm * 32;
    const int cn0 = bn * 128 + wn * 64;
#pragma unroll
    for (int j = 0; j < 4; ++j) {
        int col = cn0 + j * 16 + fcol;
        float bv = bias[col];
#pragma unroll
        for (int i = 0; i < 2; ++i)
#pragma unroll
            for (int r = 0; r < 4; ++r) {
                int row = cm0 + i * 16 + frow4 + r;
                C[(size_t)row * N + col] = acc[i][j][r] + bv;
            }
    }
}

// -------- banded attention: 2 tokens/block, thread = 8-dim chunk, 16B loads --------
__global__ __launch_bounds__(256) void attn_banded(
    const __hip_bfloat16* __restrict__ qkv,   // (B*T, 3*DIM): [q | k | v]
    __hip_bfloat16* __restrict__ o)           // (B*T, DIM)
{
    const int tid = threadIdx.x;
    const int t8  = tid & 127;           // dim-chunk: dims [8*t8, 8*t8+8)
    const int r   = blockIdx.x * 2 + (tid >> 7);   // b*T + t
    const int t   = r & (T_SEQ - 1);
    const size_t rb = (size_t)r * (3 * DIMSZ);
    const int d0 = t8 * 8;

    bf16x8 qu = *(const bf16x8*)(qkv + rb + d0);
    float q[8];
#pragma unroll
    for (int i = 0; i < 8; ++i) q[i] = bf2f((unsigned short)qu[i]);

    float s[3], vv[3][8];
#pragma unroll
    for (int j = 0; j < 3; ++j) {
        bool ok = (t + j) < T_SEQ;       // masks seq end (and batch boundary)
        size_t rbj = ok ? rb + (size_t)j * (3 * DIMSZ) : rb;
        bf16x8 ku = *(const bf16x8*)(qkv + rbj + DIMSZ + d0);
        bf16x8 vu = *(const bf16x8*)(qkv + rbj + 2 * DIMSZ + d0);
        float d = 0.f;
#pragma unroll
        for (int i = 0; i < 8; ++i) {
            vv[j][i] = bf2f((unsigned short)vu[i]);
            d += q[i] * bf2f((unsigned short)ku[i]);
        }
        // head = 64 dims = 8 lanes x 8 dims: reduce within aligned 8-lane group
        d += __shfl_xor(d, 4, 64);
        d += __shfl_xor(d, 2, 64);
        d += __shfl_xor(d, 1, 64);
        s[j] = ok ? d * 0.125f : -1e30f; // scale = 64^-0.5
    }
    float m  = fmaxf(s[0], fmaxf(s[1], s[2]));
    float p0 = __expf(s[0] - m), p1 = __expf(s[1] - m), p2 = __expf(s[2] - m);
    float inv = 1.0f / (p0 + p1 + p2);
    union { __hip_bfloat16 h[8]; bf16x8 u; } pk;
#pragma unroll
    for (int i = 0; i < 8; ++i)
        pk.h[i] = __hip_bfloat16((p0 * vv[0][i] + p1 * vv[1][i] + p2 * vv[2][i]) * inv);
    *(bf16x8*)(o + (size_t)r * DIMSZ + d0) = pk.u;
}

extern "C" void kernel_launch(void* const* d_in, const int* in_sizes, int n_in,
                              void* d_out, int out_size, void* d_ws, size_t ws_size,
                              hipStream_t stream) {
    const float* x      = (const float*)d_in[0];  // (B,T,DIM) fp32
    const float* w_qkv  = (const float*)d_in[1];  // (DIM, 3*DIM) fp32
    const float* w_proj = (const float*)d_in[2];  // (DIM, DIM) fp32
    const float* b_proj = (const float*)d_in[3];  // (DIM,) fp32
    float* out = (float*)d_out;                   // (B,T,DIM) fp32

    const int M = NBATCH * T_SEQ;   // 4096

    // workspace (bf16 intermediates):
    //   [0,8M)    xb (x bf16) -> reused as attn output after GEMM1 consumes it
    //   [8M,14M)  wqkvT  (3072x1024)
    //   [14M,16M) wprojT (1024x1024)
    //   [16M,40M) qkv    (4096x3072)
    char* ws = (char*)d_ws;
    __hip_bfloat16* xb     = (__hip_bfloat16*)(ws);
    __hip_bfloat16* attn   = (__hip_bfloat16*)(ws);            // reuse of xb region
    __hip_bfloat16* wqkvT  = (__hip_bfloat16*)(ws + (8u  << 20));
    __hip_bfloat16* wprojT = (__hip_bfloat16*)(ws + (14u << 20));
    __hip_bfloat16* qkv    = (__hip_bfloat16*)(ws + (16u << 20));

    // 1) fused prep: x->bf16, both weight convert+transposes (64x64 tiles)
    prep<<<5120, 256, 0, stream>>>(x, xb, w_qkv, wqkvT, w_proj, wprojT);

    // 2) qkv = x @ w_qkv   (4096 x 3072, K=1024): 24x32=768 blocks = 3/CU
    gemm_bt_128<<<dim3(3 * DIMSZ / 128, M / 128), 256, 0, stream>>>(
        xb, wqkvT, qkv, M, 3 * DIMSZ, DIMSZ);

    // 3) banded attention (3-key window) -> bf16 attn (reuses xb region)
    attn_banded<<<M / 2, 256, 0, stream>>>(qkv, attn);

    // 4) out = attn @ w_proj + b_proj  (4096 x 1024): 8x64=512 blocks = 2/CU
    gemm_bt_64<<<dim3(DIMSZ / 128, M / 64), 256, 0, stream>>>(
        attn, wprojT, b_proj, out, M, DIMSZ, DIMSZ);
}